// Round 6
// baseline (125.565 us; speedup 1.0000x reference)
//
#include <hip/hip_runtime.h>
#include <hip/hip_bf16.h>
#include <stdint.h>

#define HEIGHT 32
#define WIDTH  8192
#define KDIM   256
#define NDIM   512
#define NSLICES 65536                       // B * S = 64 * 1024
#define WT_BYTES (NDIM * KDIM * 2)          // 256 KB
#define FEATS_BYTES ((size_t)NSLICES * KDIM * 2)  // 33.5 MB

typedef float f32x4  __attribute__((ext_vector_type(4)));
typedef float f32x16 __attribute__((ext_vector_type(16)));
typedef short bf16x8 __attribute__((ext_vector_type(8)));

__device__ __forceinline__ ushort f2bf(float x) {
  union { float f; uint32_t u; } un; un.f = x;
  uint32_t u = un.u;
  u += 0x7FFFu + ((u >> 16) & 1u);   // round-to-nearest-even
  return (ushort)(u >> 16);
}

__device__ __forceinline__ void load_row8(float* r, const float* p) {
  f32x4 lo = *reinterpret_cast<const f32x4*>(p);
  f32x4 hi = *reinterpret_cast<const f32x4*>(p + 4);
#pragma unroll
  for (int w = 0; w < 4; ++w) { r[w] = lo[w]; r[4 + w] = hi[w]; }
}

// lin_w [K=256][N=512] f32 -> wt [N=512][K=256] bf16. 64 blocks x 256 thr x 8 elems.
__device__ __forceinline__ void prep_wt_body(const float* __restrict__ lin_w,
                                             ushort* __restrict__ wt, int bid, int tid) {
  const int base = bid * 2048 + tid * 8;
#pragma unroll
  for (int j = 0; j < 8; ++j) {
    const int idx = base + j;
    const int n = idx >> 8, k = idx & 255;
    wt[n * KDIM + k] = f2bf(lin_w[(size_t)k * NDIM + n]);
  }
}

__global__ __launch_bounds__(256) void prep_wt_kernel(const float* __restrict__ lin_w,
                                                      ushort* __restrict__ wt) {
  prep_wt_body(lin_w, wt, blockIdx.x, threadIdx.x);
}

// ---------------- kernel 1: streaming conv (+ folded wt prep) ----------------
// Blocks 0..1023: conv, 64 slices each; thread = (slice, 8-row quarter).
// Blocks 1024..1087: wt prep.
__global__ __launch_bounds__(256) void conv_kernel(
    const float* __restrict__ images, const float* __restrict__ conv_w,
    const float* __restrict__ conv_b, const float* __restrict__ lin_w,
    ushort* __restrict__ wt, ushort* __restrict__ feats) {
  const int blk = blockIdx.x;
  const int tid = threadIdx.x;
  if (blk >= 1024) { prep_wt_body(lin_w, wt, blk - 1024, tid); return; }

  float cw[9];
#pragma unroll
  for (int i = 0; i < 9; ++i) cw[i] = conv_w[i];
  const float cb = conv_b[0];

  const int sl = tid & 63;            // local slice; lanes = consecutive slices
  const int q  = tid >> 6;            // 0..3: rows q*8 .. q*8+7
  const int s  = blk * 64 + sl;       // global slice
  const int b  = s >> 10;             // batch (1024 slices per batch)
  const int slb = s & 1023;
  const float* base = images + (size_t)b * (HEIGHT * WIDTH) + (size_t)slb * 8;
  ushort* fo = feats + (size_t)s * KDIM;
  const int h0 = q * 8;

  float pr[8], cu[8], nx[8];
  if (h0 > 0) load_row8(pr, base + (size_t)(h0 - 1) * WIDTH);
  else {
#pragma unroll
    for (int w = 0; w < 8; ++w) pr[w] = 0.f;
  }
  load_row8(cu, base + (size_t)h0 * WIDTH);

#pragma unroll
  for (int i = 0; i < 8; ++i) {
    const int h = h0 + i;
    if (h + 1 < HEIGHT) load_row8(nx, base + (size_t)(h + 1) * WIDTH);
    else {
#pragma unroll
      for (int w = 0; w < 8; ++w) nx[w] = 0.f;
    }
    float y[8];
#pragma unroll
    for (int w = 0; w < 8; ++w) y[w] = cb;
#pragma unroll
    for (int dw = 0; dw < 3; ++dw) {
      const float c0 = cw[dw], c1 = cw[3 + dw], c2 = cw[6 + dw];
#pragma unroll
      for (int w = 0; w < 8; ++w) {
        const int iw = w + dw - 1;            // per-slice zero padding in w
        if (iw >= 0 && iw < 8) {
          y[w] = fmaf(pr[iw], c0, y[w]);
          y[w] = fmaf(cu[iw], c1, y[w]);
          y[w] = fmaf(nx[iw], c2, y[w]);
        }
      }
    }
    bf16x8 pack;
#pragma unroll
    for (int w = 0; w < 8; ++w) pack[w] = (short)f2bf(fmaxf(y[w], 0.f));
    *reinterpret_cast<bf16x8*>(fo + h * 8) = pack;
#pragma unroll
    for (int w = 0; w < 8; ++w) { pr[w] = cu[w]; cu[w] = nx[w]; }
  }
}

// ---------------- kernel 2: barrier-free streaming GEMM ----------------
// Wave-task = (mtile, n-pass): 2048 blocks x 4 waves; wave wv does the 128-col
// pass wv of its block's mtile. All 4 waves read identical A addresses (L1 reuse).
// Block->mtile mapping matches producer XCD: conv block c (XCD c&7) made slices
// of mtiles 2c,2c+1; gemm block g (XCD g&7) takes mtile 2*(g&1023)+(g>>10).
__global__ __launch_bounds__(256) void gemm_kernel(
    const ushort* __restrict__ feats, const ushort* __restrict__ wt,
    const float* __restrict__ lin_b, float* __restrict__ out) {
  const int g    = blockIdx.x;
  const int mtile = 2 * (g & 1023) + (g >> 10);
  const int tid  = threadIdx.x;
  const int lane = tid & 63;
  const int wv   = tid >> 6;
  const int la   = lane & 31;
  const int lb   = lane >> 5;
  const int n0   = wv * 128;

  const ushort* arow = feats + (size_t)mtile * 32 * KDIM + (size_t)la * KDIM + lb * 8;
  const size_t row0 = (size_t)mtile * 32;

  f32x16 acc[4];
#pragma unroll
  for (int nf = 0; nf < 4; ++nf)
#pragma unroll
    for (int i = 0; i < 16; ++i) acc[nf][i] = 0.f;

  const ushort* wb = wt + (size_t)(n0 + la) * KDIM + lb * 8;

#pragma unroll
  for (int k0 = 0; k0 < 16; ++k0) {
    const bf16x8 af = *reinterpret_cast<const bf16x8*>(arow + k0 * 16);
    bf16x8 bfr[4];
#pragma unroll
    for (int nf = 0; nf < 4; ++nf)
      bfr[nf] = *reinterpret_cast<const bf16x8*>(wb + (size_t)nf * 32 * KDIM + k0 * 16);
#pragma unroll
    for (int nf = 0; nf < 4; ++nf)
      acc[nf] = __builtin_amdgcn_mfma_f32_32x32x16_bf16(af, bfr[nf], acc[nf], 0, 0, 0);
  }

#pragma unroll
  for (int nf = 0; nf < 4; ++nf) {
    const int col = n0 + nf * 32 + la;
    const float bias = lin_b[col];
#pragma unroll
    for (int reg = 0; reg < 16; ++reg) {
      const int rr = (reg & 3) + 8 * (reg >> 2) + 4 * lb;
      out[(row0 + rr) * NDIM + col] = acc[nf][reg] + bias;
    }
  }
}

// ---------------- fallback path (ws too small): round-1 fused kernel ----------------
#define BM 64
__global__ __launch_bounds__(512) void fused_kernel(
    const float* __restrict__ images, const float* __restrict__ conv_w,
    const float* __restrict__ conv_b, const ushort* __restrict__ wt,
    const float* __restrict__ lin_b, float* __restrict__ out) {
  __shared__ ushort A[BM * KDIM];

  const int tid = threadIdx.x;
  const int rb  = blockIdx.x;
  const int b   = rb >> 4;
  const int s0  = (rb & 15) * BM;

  float cw[9];
#pragma unroll
  for (int i = 0; i < 9; ++i) cw[i] = conv_w[i];
  const float cb = conv_b[0];

  {
    const int sl = tid & 63;
    const int hg = tid >> 6;
    const int h0 = hg * 4;
    const float* base = images + (size_t)b * HEIGHT * WIDTH + (size_t)(s0 + sl) * 8;

    float r[6][8];
#pragma unroll
    for (int i = 0; i < 6; ++i) {
      const int h = h0 - 1 + i;
      if (h >= 0 && h < HEIGHT) load_row8(r[i], base + (size_t)h * WIDTH);
      else {
#pragma unroll
        for (int w = 0; w < 8; ++w) r[i][w] = 0.f;
      }
    }

#pragma unroll
    for (int oh = 0; oh < 4; ++oh) {
      float y[8];
#pragma unroll
      for (int w = 0; w < 8; ++w) y[w] = cb;
#pragma unroll
      for (int dh = 0; dh < 3; ++dh) {
#pragma unroll
        for (int dw = 0; dw < 3; ++dw) {
          const float c = cw[dh * 3 + dw];
#pragma unroll
          for (int w = 0; w < 8; ++w) {
            const int iw = w + dw - 1;
            if (iw >= 0 && iw < 8) y[w] = fmaf(r[oh + dh][iw], c, y[w]);
          }
        }
      }
      bf16x8 pack;
#pragma unroll
      for (int w = 0; w < 8; ++w) pack[w] = (short)f2bf(fmaxf(y[w], 0.f));
      int byte = sl * 512 + (h0 + oh) * 16;
      byte ^= (sl & 7) << 4;
      *reinterpret_cast<bf16x8*>(reinterpret_cast<char*>(A) + byte) = pack;
    }
  }
  __syncthreads();

  const int lane = tid & 63;
  const int wid  = tid >> 6;
  const int n0   = wid * 64;
  const int la   = lane & 31;
  const int lb   = lane >> 5;

  f32x16 acc[2][2];
#pragma unroll
  for (int mf = 0; mf < 2; ++mf)
#pragma unroll
    for (int nf = 0; nf < 2; ++nf)
#pragma unroll
      for (int i = 0; i < 16; ++i) acc[mf][nf][i] = 0.f;

  const ushort* wbase = wt + (size_t)(n0 + la) * KDIM + lb * 8;

#pragma unroll
  for (int k0 = 0; k0 < 16; ++k0) {
    bf16x8 af[2], bfr[2];
#pragma unroll
    for (int mf = 0; mf < 2; ++mf) {
      const int row = mf * 32 + la;
      int byte = row * 512 + k0 * 32 + lb * 16;
      byte ^= (row & 7) << 4;
      af[mf] = *reinterpret_cast<const bf16x8*>(reinterpret_cast<const char*>(A) + byte);
    }
#pragma unroll
    for (int nf = 0; nf < 2; ++nf)
      bfr[nf] = *reinterpret_cast<const bf16x8*>(wbase + (size_t)nf * 32 * KDIM + k0 * 16);
#pragma unroll
    for (int mf = 0; mf < 2; ++mf)
#pragma unroll
      for (int nf = 0; nf < 2; ++nf)
        acc[mf][nf] = __builtin_amdgcn_mfma_f32_32x32x16_bf16(af[mf], bfr[nf], acc[mf][nf], 0, 0, 0);
  }

  const size_t row0 = (size_t)rb * BM;
#pragma unroll
  for (int mf = 0; mf < 2; ++mf) {
#pragma unroll
    for (int nf = 0; nf < 2; ++nf) {
      const int col = n0 + nf * 32 + la;
      const float bias = lin_b[col];
#pragma unroll
      for (int reg = 0; reg < 16; ++reg) {
        const int rr = mf * 32 + (reg & 3) + 8 * (reg >> 2) + 4 * lb;
        out[(row0 + rr) * NDIM + col] = acc[mf][nf][reg] + bias;
      }
    }
  }
}

extern "C" void kernel_launch(void* const* d_in, const int* in_sizes, int n_in,
                              void* d_out, int out_size, void* d_ws, size_t ws_size,
                              hipStream_t stream) {
  const float* images = (const float*)d_in[0];
  const float* conv_w = (const float*)d_in[1];
  const float* conv_b = (const float*)d_in[2];
  const float* lin_w  = (const float*)d_in[3];
  const float* lin_b  = (const float*)d_in[4];
  float* out = (float*)d_out;
  ushort* wt = (ushort*)d_ws;

  if (ws_size >= (size_t)WT_BYTES + FEATS_BYTES) {
    ushort* feats = (ushort*)((char*)d_ws + WT_BYTES);
    hipLaunchKernelGGL(conv_kernel, dim3(1088), dim3(256), 0, stream,
                       images, conv_w, conv_b, lin_w, wt, feats);
    hipLaunchKernelGGL(gemm_kernel, dim3(2048), dim3(256), 0, stream,
                       feats, wt, lin_b, out);
  } else {
    hipLaunchKernelGGL(prep_wt_kernel, dim3(64), dim3(256), 0, stream, lin_w, wt);
    hipLaunchKernelGGL(fused_kernel, dim3(1024), dim3(512), 0, stream,
                       images, conv_w, conv_b, wt, lin_b, out);
  }
}

// Round 7
// 59.001 us; speedup vs baseline: 2.1282x; 2.1282x over previous
//
#include <hip/hip_runtime.h>
#include <hip/hip_bf16.h>
#include <stdint.h>

#define HEIGHT 32
#define WIDTH  8192
#define KDIM   256
#define NDIM   512
#define NSLICES 65536                       // B * S = 64 * 1024
#define NMTILES (NSLICES / 32)              // 2048
#define WT_BYTES (NDIM * KDIM * 2)          // 256 KB
#define FEATS_BYTES ((size_t)NSLICES * KDIM * 2)  // 33.5 MB

typedef float f32x4  __attribute__((ext_vector_type(4)));
typedef float f32x16 __attribute__((ext_vector_type(16)));
typedef short bf16x8 __attribute__((ext_vector_type(8)));

__device__ __forceinline__ ushort f2bf(float x) {
  union { float f; uint32_t u; } un; un.f = x;
  uint32_t u = un.u;
  u += 0x7FFFu + ((u >> 16) & 1u);   // round-to-nearest-even
  return (ushort)(u >> 16);
}

__device__ __forceinline__ void load_row8(float* r, const float* p) {
  f32x4 lo = *reinterpret_cast<const f32x4*>(p);
  f32x4 hi = *reinterpret_cast<const f32x4*>(p + 4);
#pragma unroll
  for (int w = 0; w < 4; ++w) { r[w] = lo[w]; r[4 + w] = hi[w]; }
}

// ---- wt2: B-fragment-tiled layout ----
// wt2[((nb*16 + k0)*64 + lane)*8 + e] = bf16(lin_w[k][n]),
//   n = nb*32 + (lane&31), k = k0*16 + (lane>>5)*8 + e.
// One wave B-frag load = 1024 contiguous bytes.
__device__ __forceinline__ void prep_wt2_body(const float* __restrict__ lin_w,
                                              ushort* __restrict__ wt2, int bid, int tid) {
  const int idx = bid * 256 + tid;          // 0..16383
  const int ln  = idx & 63;
  const int k0  = (idx >> 6) & 15;
  const int nb  = idx >> 10;
  const int n   = nb * 32 + (ln & 31);
  const int kb  = k0 * 16 + (ln >> 5) * 8;
  bf16x8 p;
#pragma unroll
  for (int e = 0; e < 8; ++e) p[e] = (short)f2bf(lin_w[(size_t)(kb + e) * NDIM + n]);
  *reinterpret_cast<bf16x8*>(wt2 + (size_t)idx * 8) = p;
}

// old layout for fallback path: wt[n*256 + k]
__global__ __launch_bounds__(256) void prep_wt_kernel(const float* __restrict__ lin_w,
                                                      ushort* __restrict__ wt) {
  const int base = blockIdx.x * 2048 + threadIdx.x * 8;
#pragma unroll
  for (int j = 0; j < 8; ++j) {
    const int idx = base + j;
    const int n = idx >> 8, k = idx & 255;
    wt[n * KDIM + k] = f2bf(lin_w[(size_t)k * NDIM + n]);
  }
}

// ---------------- kernel 1: streaming conv -> A-fragment-tiled feats2 ----------------
// Blocks 0..2047: conv, one mtile (32 slices) each; thread = (slice, 4-row group).
// Blocks 2048..2111: wt2 prep.
// feats2[((mt*16 + k0)*64 + ln)*8 + e], ln = ((h&1)<<5)|(slice&31), k0 = h>>1, e = w.
__global__ __launch_bounds__(256) void conv_kernel(
    const float* __restrict__ images, const float* __restrict__ conv_w,
    const float* __restrict__ conv_b, const float* __restrict__ lin_w,
    ushort* __restrict__ wt2, ushort* __restrict__ feats2) {
  const int blk = blockIdx.x;
  const int tid = threadIdx.x;
  if (blk >= NMTILES) { prep_wt2_body(lin_w, wt2, blk - NMTILES, tid); return; }

  float cw[9];
#pragma unroll
  for (int i = 0; i < 9; ++i) cw[i] = conv_w[i];
  const float cb = conv_b[0];

  const int sl = tid & 31;            // slice within mtile (= blk)
  const int q  = tid >> 5;            // 0..7: output rows q*4 .. q*4+3
  const int s  = blk * 32 + sl;       // global slice
  const int b  = s >> 10;             // batch (1024 slices per batch)
  const int slb = s & 1023;
  const float* base = images + (size_t)b * (HEIGHT * WIDTH) + (size_t)slb * 8;
  const int h0 = q * 4;

  float r[6][8];
#pragma unroll
  for (int i = 0; i < 6; ++i) {
    const int h = h0 - 1 + i;
    if (h >= 0 && h < HEIGHT) load_row8(r[i], base + (size_t)h * WIDTH);
    else {
#pragma unroll
      for (int w = 0; w < 8; ++w) r[i][w] = 0.f;
    }
  }

#pragma unroll
  for (int oh = 0; oh < 4; ++oh) {
    const int h = h0 + oh;
    float y[8];
#pragma unroll
    for (int w = 0; w < 8; ++w) y[w] = cb;
#pragma unroll
    for (int dh = 0; dh < 3; ++dh) {
#pragma unroll
      for (int dw = 0; dw < 3; ++dw) {
        const float c = cw[dh * 3 + dw];
#pragma unroll
        for (int w = 0; w < 8; ++w) {
          const int iw = w + dw - 1;            // per-slice zero padding in w
          if (iw >= 0 && iw < 8) y[w] = fmaf(r[oh + dh][iw], c, y[w]);
        }
      }
    }
    bf16x8 pack;
#pragma unroll
    for (int w = 0; w < 8; ++w) pack[w] = (short)f2bf(fmaxf(y[w], 0.f));
    const int ln = ((h & 1) << 5) | sl;
    const int k0 = h >> 1;
    *reinterpret_cast<bf16x8*>(feats2 + (((size_t)blk * 16 + k0) * 64 + ln) * 8) = pack;
  }
}

// ---------------- kernel 2: barrier-free streaming GEMM, fully-coalesced frags ----------------
// Block g = mtile g (identity keeps producer/consumer on the same XCD).
// 4 waves; wave wv does 128 cols (n-blocks wv*4 .. wv*4+3).
__global__ __launch_bounds__(256) void gemm_kernel(
    const ushort* __restrict__ feats2, const ushort* __restrict__ wt2,
    const float* __restrict__ lin_b, float* __restrict__ out) {
  const int mtile = blockIdx.x;
  const int tid  = threadIdx.x;
  const int lane = tid & 63;
  const int wv   = tid >> 6;
  const int la   = lane & 31;
  const int lb   = lane >> 5;

  const ushort* abase = feats2 + ((size_t)mtile * 16) * 512 + (size_t)lane * 8;
  const ushort* bbase = wt2 + ((size_t)(wv * 4) * 16) * 512 + (size_t)lane * 8;

  f32x16 acc[4];
#pragma unroll
  for (int nf = 0; nf < 4; ++nf)
#pragma unroll
    for (int i = 0; i < 16; ++i) acc[nf][i] = 0.f;

#pragma unroll
  for (int k0 = 0; k0 < 16; ++k0) {
    const bf16x8 af = *reinterpret_cast<const bf16x8*>(abase + (size_t)k0 * 512);
    bf16x8 bfr[4];
#pragma unroll
    for (int nf = 0; nf < 4; ++nf)
      bfr[nf] = *reinterpret_cast<const bf16x8*>(bbase + (size_t)(nf * 16 + k0) * 512);
#pragma unroll
    for (int nf = 0; nf < 4; ++nf)
      acc[nf] = __builtin_amdgcn_mfma_f32_32x32x16_bf16(af, bfr[nf], acc[nf], 0, 0, 0);
  }

  const size_t row0 = (size_t)mtile * 32;
#pragma unroll
  for (int nf = 0; nf < 4; ++nf) {
    const int col = wv * 128 + nf * 32 + la;
    const float bias = lin_b[col];
#pragma unroll
    for (int reg = 0; reg < 16; ++reg) {
      const int rr = (reg & 3) + 8 * (reg >> 2) + 4 * lb;
      out[(row0 + rr) * NDIM + col] = acc[nf][reg] + bias;
    }
  }
}

// ---------------- fallback path (ws too small): round-1 fused kernel ----------------
#define BM 64
__global__ __launch_bounds__(512) void fused_kernel(
    const float* __restrict__ images, const float* __restrict__ conv_w,
    const float* __restrict__ conv_b, const ushort* __restrict__ wt,
    const float* __restrict__ lin_b, float* __restrict__ out) {
  __shared__ ushort A[BM * KDIM];

  const int tid = threadIdx.x;
  const int rb  = blockIdx.x;
  const int b   = rb >> 4;
  const int s0  = (rb & 15) * BM;

  float cw[9];
#pragma unroll
  for (int i = 0; i < 9; ++i) cw[i] = conv_w[i];
  const float cb = conv_b[0];

  {
    const int sl = tid & 63;
    const int hg = tid >> 6;
    const int h0 = hg * 4;
    const float* base = images + (size_t)b * HEIGHT * WIDTH + (size_t)(s0 + sl) * 8;

    float r[6][8];
#pragma unroll
    for (int i = 0; i < 6; ++i) {
      const int h = h0 - 1 + i;
      if (h >= 0 && h < HEIGHT) load_row8(r[i], base + (size_t)h * WIDTH);
      else {
#pragma unroll
        for (int w = 0; w < 8; ++w) r[i][w] = 0.f;
      }
    }

#pragma unroll
    for (int oh = 0; oh < 4; ++oh) {
      float y[8];
#pragma unroll
      for (int w = 0; w < 8; ++w) y[w] = cb;
#pragma unroll
      for (int dh = 0; dh < 3; ++dh) {
#pragma unroll
        for (int dw = 0; dw < 3; ++dw) {
          const float c = cw[dh * 3 + dw];
#pragma unroll
          for (int w = 0; w < 8; ++w) {
            const int iw = w + dw - 1;
            if (iw >= 0 && iw < 8) y[w] = fmaf(r[oh + dh][iw], c, y[w]);
          }
        }
      }
      bf16x8 pack;
#pragma unroll
      for (int w = 0; w < 8; ++w) pack[w] = (short)f2bf(fmaxf(y[w], 0.f));
      int byte = sl * 512 + (h0 + oh) * 16;
      byte ^= (sl & 7) << 4;
      *reinterpret_cast<bf16x8*>(reinterpret_cast<char*>(A) + byte) = pack;
    }
  }
  __syncthreads();

  const int lane = tid & 63;
  const int wid  = tid >> 6;
  const int n0   = wid * 64;
  const int la   = lane & 31;
  const int lb   = lane >> 5;

  f32x16 acc[2][2];
#pragma unroll
  for (int mf = 0; mf < 2; ++mf)
#pragma unroll
    for (int nf = 0; nf < 2; ++nf)
#pragma unroll
      for (int i = 0; i < 16; ++i) acc[mf][nf][i] = 0.f;

  const ushort* wbase = wt + (size_t)(n0 + la) * KDIM + lb * 8;

#pragma unroll
  for (int k0 = 0; k0 < 16; ++k0) {
    bf16x8 af[2], bfr[2];
#pragma unroll
    for (int mf = 0; mf < 2; ++mf) {
      const int row = mf * 32 + la;
      int byte = row * 512 + k0 * 32 + lb * 16;
      byte ^= (row & 7) << 4;
      af[mf] = *reinterpret_cast<const bf16x8*>(reinterpret_cast<const char*>(A) + byte);
    }
#pragma unroll
    for (int nf = 0; nf < 2; ++nf)
      bfr[nf] = *reinterpret_cast<const bf16x8*>(wbase + (size_t)nf * 32 * KDIM + k0 * 16);
#pragma unroll
    for (int mf = 0; mf < 2; ++mf)
#pragma unroll
      for (int nf = 0; nf < 2; ++nf)
        acc[mf][nf] = __builtin_amdgcn_mfma_f32_32x32x16_bf16(af[mf], bfr[nf], acc[mf][nf], 0, 0, 0);
  }

  const size_t row0 = (size_t)rb * BM;
#pragma unroll
  for (int mf = 0; mf < 2; ++mf) {
#pragma unroll
    for (int nf = 0; nf < 2; ++nf) {
      const int col = n0 + nf * 32 + la;
      const float bias = lin_b[col];
#pragma unroll
      for (int reg = 0; reg < 16; ++reg) {
        const int rr = mf * 32 + (reg & 3) + 8 * (reg >> 2) + 4 * lb;
        out[(row0 + rr) * NDIM + col] = acc[mf][nf][reg] + bias;
      }
    }
  }
}

extern "C" void kernel_launch(void* const* d_in, const int* in_sizes, int n_in,
                              void* d_out, int out_size, void* d_ws, size_t ws_size,
                              hipStream_t stream) {
  const float* images = (const float*)d_in[0];
  const float* conv_w = (const float*)d_in[1];
  const float* conv_b = (const float*)d_in[2];
  const float* lin_w  = (const float*)d_in[3];
  const float* lin_b  = (const float*)d_in[4];
  float* out = (float*)d_out;
  ushort* wt = (ushort*)d_ws;

  if (ws_size >= (size_t)WT_BYTES + FEATS_BYTES) {
    ushort* feats2 = (ushort*)((char*)d_ws + WT_BYTES);
    hipLaunchKernelGGL(conv_kernel, dim3(NMTILES + 64), dim3(256), 0, stream,
                       images, conv_w, conv_b, lin_w, wt, feats2);
    hipLaunchKernelGGL(gemm_kernel, dim3(NMTILES), dim3(256), 0, stream,
                       feats2, wt, lin_b, out);
  } else {
    hipLaunchKernelGGL(prep_wt_kernel, dim3(64), dim3(256), 0, stream, lin_w, wt);
    hipLaunchKernelGGL(fused_kernel, dim3(1024), dim3(512), 0, stream,
                       images, conv_w, conv_b, wt, lin_b, out);
  }
}

// Round 8
// 54.220 us; speedup vs baseline: 2.3159x; 1.0882x over previous
//
#include <hip/hip_runtime.h>
#include <hip/hip_bf16.h>
#include <stdint.h>

#define HEIGHT 32
#define WIDTH  8192
#define KDIM   256
#define NDIM   512
#define NSLICES 65536                       // B * S = 64 * 1024
#define NMTILES (NSLICES / 32)              // 2048
#define WT_BYTES (NDIM * KDIM * 2)          // 256 KB

typedef float f32x4  __attribute__((ext_vector_type(4)));
typedef float f32x16 __attribute__((ext_vector_type(16)));
typedef short bf16x8 __attribute__((ext_vector_type(8)));

__device__ __forceinline__ ushort f2bf(float x) {
  union { float f; uint32_t u; } un; un.f = x;
  uint32_t u = un.u;
  u += 0x7FFFu + ((u >> 16) & 1u);   // round-to-nearest-even
  return (ushort)(u >> 16);
}

__device__ __forceinline__ void load_row8(float* r, const float* p) {
  f32x4 lo = *reinterpret_cast<const f32x4*>(p);
  f32x4 hi = *reinterpret_cast<const f32x4*>(p + 4);
#pragma unroll
  for (int w = 0; w < 4; ++w) { r[w] = lo[w]; r[4 + w] = hi[w]; }
}

// ---- wt2: B-fragment-tiled layout (proven in R7) ----
// wt2[((nb*16 + k0)*64 + lane)*8 + e] = bf16(lin_w[k][n]),
//   n = nb*32 + (lane&31), k = k0*16 + (lane>>5)*8 + e.
// One wave B-frag load = 1024 contiguous bytes.
__global__ __launch_bounds__(256) void prep_wt2_kernel(const float* __restrict__ lin_w,
                                                       ushort* __restrict__ wt2) {
  const int idx = blockIdx.x * 256 + threadIdx.x;   // 0..16383
  const int ln  = idx & 63;
  const int k0  = (idx >> 6) & 15;
  const int nb  = idx >> 10;
  const int n   = nb * 32 + (ln & 31);
  const int kb  = k0 * 16 + (ln >> 5) * 8;
  bf16x8 p;
#pragma unroll
  for (int e = 0; e < 8; ++e) p[e] = (short)f2bf(lin_w[(size_t)(kb + e) * NDIM + n]);
  *reinterpret_cast<bf16x8*>(wt2 + (size_t)idx * 8) = p;
}

// ---------------- fused: conv -> LDS A-frags -> MFMA -> out ----------------
// Block = 1 mtile (32 slices). LDS holds A in fragment order:
// A[(k0*64 + ln)*8 + e], ln = ((h&1)<<5)|sl, k0 = h>>1, e = w  (16 KB).
// GEMM phase: lane's A-frag = 16 contiguous bytes at (k0*64+lane)*16 -> ds_read_b128,
// conflict-free; B-frags 1 KB contiguous from L2-resident wt2.
__global__ __launch_bounds__(256) void fused_kernel(
    const float* __restrict__ images, const float* __restrict__ conv_w,
    const float* __restrict__ conv_b, const ushort* __restrict__ wt2,
    const float* __restrict__ lin_b, float* __restrict__ out) {
  __shared__ ushort A[16 * 64 * 8];   // 16 KB

  const int tid  = threadIdx.x;
  const int blk  = blockIdx.x;        // mtile

  float cw[9];
#pragma unroll
  for (int i = 0; i < 9; ++i) cw[i] = conv_w[i];
  const float cb = conv_b[0];

  // ---------- phase 1: conv 32 slices x 32 rows -> A-frags in LDS ----------
  {
    const int sl = tid & 31;          // slice within mtile
    const int q  = tid >> 5;          // 0..7: output rows q*4 .. q*4+3
    const int s  = blk * 32 + sl;     // global slice
    const int b  = s >> 10;           // batch (1024 slices per batch)
    const int slb = s & 1023;
    const float* base = images + (size_t)b * (HEIGHT * WIDTH) + (size_t)slb * 8;
    const int h0 = q * 4;

    float r[6][8];
#pragma unroll
    for (int i = 0; i < 6; ++i) {
      const int h = h0 - 1 + i;
      if (h >= 0 && h < HEIGHT) load_row8(r[i], base + (size_t)h * WIDTH);
      else {
#pragma unroll
        for (int w = 0; w < 8; ++w) r[i][w] = 0.f;
      }
    }

#pragma unroll
    for (int oh = 0; oh < 4; ++oh) {
      const int h = h0 + oh;
      float y[8];
#pragma unroll
      for (int w = 0; w < 8; ++w) y[w] = cb;
#pragma unroll
      for (int dh = 0; dh < 3; ++dh) {
#pragma unroll
        for (int dw = 0; dw < 3; ++dw) {
          const float c = cw[dh * 3 + dw];
#pragma unroll
          for (int w = 0; w < 8; ++w) {
            const int iw = w + dw - 1;          // per-slice zero padding in w
            if (iw >= 0 && iw < 8) y[w] = fmaf(r[oh + dh][iw], c, y[w]);
          }
        }
      }
      bf16x8 pack;
#pragma unroll
      for (int w = 0; w < 8; ++w) pack[w] = (short)f2bf(fmaxf(y[w], 0.f));
      const int ln = ((h & 1) << 5) | sl;
      const int k0 = h >> 1;
      *reinterpret_cast<bf16x8*>(A + ((size_t)k0 * 64 + ln) * 8) = pack;
    }
  }
  __syncthreads();

  // ---------- phase 2: [32 x 256] @ [256 x 512], wave = 128 cols ----------
  const int lane = tid & 63;
  const int wv   = tid >> 6;
  const int la   = lane & 31;
  const int lb   = lane >> 5;

  const ushort* abase = A + (size_t)lane * 8;
  const ushort* bbase = wt2 + ((size_t)(wv * 4) * 16) * 512 + (size_t)lane * 8;

  f32x16 acc[4];
#pragma unroll
  for (int nf = 0; nf < 4; ++nf)
#pragma unroll
    for (int i = 0; i < 16; ++i) acc[nf][i] = 0.f;

#pragma unroll
  for (int k0 = 0; k0 < 16; ++k0) {
    const bf16x8 af = *reinterpret_cast<const bf16x8*>(abase + (size_t)k0 * 512);
    bf16x8 bfr[4];
#pragma unroll
    for (int nf = 0; nf < 4; ++nf)
      bfr[nf] = *reinterpret_cast<const bf16x8*>(bbase + (size_t)(nf * 16 + k0) * 512);
#pragma unroll
    for (int nf = 0; nf < 4; ++nf)
      acc[nf] = __builtin_amdgcn_mfma_f32_32x32x16_bf16(af, bfr[nf], acc[nf], 0, 0, 0);
  }

  // ---------- epilogue: + bias, fp32 stores ----------
  const size_t row0 = (size_t)blk * 32;
#pragma unroll
  for (int nf = 0; nf < 4; ++nf) {
    const int col = wv * 128 + nf * 32 + la;
    const float bias = lin_b[col];
#pragma unroll
    for (int reg = 0; reg < 16; ++reg) {
      const int rr = (reg & 3) + 8 * (reg >> 2) + 4 * lb;
      out[(row0 + rr) * NDIM + col] = acc[nf][reg] + bias;
    }
  }
}

extern "C" void kernel_launch(void* const* d_in, const int* in_sizes, int n_in,
                              void* d_out, int out_size, void* d_ws, size_t ws_size,
                              hipStream_t stream) {
  const float* images = (const float*)d_in[0];
  const float* conv_w = (const float*)d_in[1];
  const float* conv_b = (const float*)d_in[2];
  const float* lin_w  = (const float*)d_in[3];
  const float* lin_b  = (const float*)d_in[4];
  float* out = (float*)d_out;
  ushort* wt2 = (ushort*)d_ws;      // 256 KB

  hipLaunchKernelGGL(prep_wt2_kernel, dim3(64), dim3(256), 0, stream, lin_w, wt2);
  hipLaunchKernelGGL(fused_kernel, dim3(NMTILES), dim3(256), 0, stream,
                     images, conv_w, conv_b, wt2, lin_b, out);
}